// Round 7
// baseline (190.455 us; speedup 1.0000x reference)
//
#include <hip/hip_runtime.h>
#include <math.h>

#define NB 8
#define TT 2048
#define DD 1024
#define NTI 16            // 2048 / 128 t-tiles
#define NPAIR 136         // NTI*(NTI+1)/2

typedef __attribute__((ext_vector_type(8))) short short8;
typedef __attribute__((ext_vector_type(4))) float floatx4;

__device__ inline unsigned short f2bf(float f) {
    unsigned u = __builtin_bit_cast(unsigned, f);
    unsigned r = (u + 0x7fffu + ((u >> 16) & 1u)) >> 16;
    return (unsigned short)r;
}

__device__ inline float bf2f(unsigned short u) {
    return __builtin_bit_cast(float, (unsigned)u << 16);
}

__device__ inline float fast_gelu(float x) {
    // tanh(z) = 1 - 2/(exp(2z)+1); __expf -> v_exp_f32
    float z = 0.7978845608028654f * (x + 0.044715f * x * x * x);
    float e = __expf(2.0f * z);
    float th = 1.0f - 2.0f / (e + 1.0f);
    return 0.5f * x * (1.0f + th);
}

// ------- kernel A: gelu + row norm + ema dot, wave-per-row -------------------
__global__ __launch_bounds__(256) void k_gelu_norm(
        const float* __restrict__ x, const float* __restrict__ ema,
        unsigned short* __restrict__ onrm, float* __restrict__ norms,
        float* __restrict__ ema_sim) {
    int row = blockIdx.x * 4 + (threadIdx.x >> 6);
    int lane = threadIdx.x & 63;
    const float4* xr = reinterpret_cast<const float4*>(x + (size_t)row * DD);
    const float4* er = reinterpret_cast<const float4*>(ema);
    float g[16];
    float ss = 0.f, dt = 0.f, e2 = 0.f;
#pragma unroll
    for (int j = 0; j < 4; ++j) {
        float4 v = xr[j * 64 + lane];
        float4 e = er[j * 64 + lane];
        float vv[4] = {v.x, v.y, v.z, v.w};
        float ee[4] = {e.x, e.y, e.z, e.w};
        e2 += ee[0] * ee[0] + ee[1] * ee[1] + ee[2] * ee[2] + ee[3] * ee[3];
#pragma unroll
        for (int i = 0; i < 4; ++i) {
            float o = fast_gelu(vv[i]);
            g[j * 4 + i] = o;
            ss += o * o;
            dt += o * ee[i];
        }
    }
#pragma unroll
    for (int m = 1; m < 64; m <<= 1) {
        ss += __shfl_xor(ss, m);
        dt += __shfl_xor(dt, m);
        e2 += __shfl_xor(e2, m);
    }
    float nrm = fmaxf(sqrtf(ss), 1e-12f);
    float inv = 1.0f / nrm;
    float einv = 1.0f / fmaxf(sqrtf(e2), 1e-12f);
    ushort4* orow = reinterpret_cast<ushort4*>(onrm + (size_t)row * DD);
#pragma unroll
    for (int j = 0; j < 4; ++j) {
        ushort4 u;
        u.x = f2bf(g[j * 4 + 0] * inv);
        u.y = f2bf(g[j * 4 + 1] * inv);
        u.z = f2bf(g[j * 4 + 2] * inv);
        u.w = f2bf(g[j * 4 + 3] * inv);
        orow[j * 64 + lane] = u;
    }
    if (lane == 0) {
        norms[row] = nrm;
        ema_sim[row] = dt * inv * einv;
    }
}

// -------- kernel B: causal max similarity, no-LDS direct-L2 MFMA GEMM --------
// grid = NB*136 lower-tri 128x128 tile pairs, XCD-swizzled (batch per XCD ->
// 4 MB onrm slice resident in that XCD's 4 MB L2). 4 waves, each 64x64 (4x4
// 16x16x32 frags). Fragments are loaded straight from L1/L2 (onrm is
// L2-resident; FETCH_SIZE 17 MB proves it) -- no LDS, no barriers, no drain.
// Per-lane addresses: row = tile + f*16 + (lane&15), col = (lane>>4)*8; a
// wave-load touches 16 rows x 64 contiguous bytes (coalesced 64B segments).
// 2-deep rotation keeps ~16 wave-loads (16 KB) in flight per wave.
__global__ __launch_bounds__(256) void k_seqmax(const unsigned short* __restrict__ onrm,
                                                float* __restrict__ part) {
    int id = blockIdx.x;
    int nid = (id & 7) * NPAIR + (id >> 3);      // bijective: 1088 % 8 == 0
    int b = nid / NPAIR;
    int p = nid % NPAIR;
    int ti = (int)((sqrtf(8.0f * (float)p + 1.0f) - 1.0f) * 0.5f);
    while ((ti + 1) * (ti + 2) / 2 <= p) ++ti;
    while (ti * (ti + 1) / 2 > p) --ti;
    int sj = p - ti * (ti + 1) / 2;

    int lane = threadIdx.x & 63;
    int wave = threadIdx.x >> 6;
    int wr = wave >> 1, wc = wave & 1;
    int rl = lane & 15, g = lane >> 4;

    // per-lane fragment base pointers (element units); frag f adds f*16 rows
    const unsigned short* Abp =
        onrm + (size_t)(b * TT + ti * 128 + wr * 64 + rl) * DD + g * 8;
    const unsigned short* Bbp =
        onrm + (size_t)(b * TT + sj * 128 + wc * 64 + rl) * DD + g * 8;

    floatx4 acc[4][4];
#pragma unroll
    for (int i = 0; i < 4; i++)
#pragma unroll
        for (int j = 0; j < 4; j++) acc[i][j] = (floatx4){0.f, 0.f, 0.f, 0.f};

    auto ld = [&](short8* da, short8* db, int off) {
#pragma unroll
        for (int f = 0; f < 4; ++f) {
            da[f] = *(const short8*)(Abp + (size_t)f * 16 * DD + off);
            db[f] = *(const short8*)(Bbp + (size_t)f * 16 * DD + off);
        }
    };
    auto mm = [&](short8* a, short8* bfr) {
#pragma unroll
        for (int fi = 0; fi < 4; ++fi)
#pragma unroll
            for (int fj = 0; fj < 4; ++fj)
                acc[fi][fj] = __builtin_amdgcn_mfma_f32_16x16x32_bf16(
                    a[fi], bfr[fj], acc[fi][fj], 0, 0, 0);
    };

    short8 a0[4], b0[4], a1[4], b1[4];
    ld(a0, b0, 0);                               // (kt=0, half 0)
    for (int kt = 0; kt < 16; ++kt) {
        ld(a1, b1, kt * 64 + 32);                // next half-K while computing
        mm(a0, b0);
        if (kt + 1 < 16) ld(a0, b0, (kt + 1) * 64);
        mm(a1, b1);
    }

    // epilogue: strict-causal mask, row-max over this wave's 64-col half,
    // write partial to part[b][sj*2+wc][t]
    int t0g = ti * 128 + wr * 64;
    int s0g = sj * 128 + wc * 64;
#pragma unroll
    for (int fi = 0; fi < 4; ++fi) {
#pragma unroll
        for (int r = 0; r < 4; ++r) {
            int trow = t0g + fi * 16 + g * 4 + r;
            float m = -2.0f;
#pragma unroll
            for (int fj = 0; fj < 4; ++fj) {
                int scol = s0g + fj * 16 + rl;
                m = fmaxf(m, (scol < trow) ? acc[fi][fj][r] : -2.0f);
            }
#pragma unroll
            for (int msk = 1; msk < 16; msk <<= 1) m = fmaxf(m, __shfl_xor(m, msk));
            if (rl == 0)
                part[(((size_t)b * 32 + sj * 2 + wc) << 11) + trow] = m;
        }
    }
}

// ------- kernel C: reduce partials + gate + reconstruct out, wave-per-row ----
__global__ __launch_bounds__(256) void k_gate(
        const unsigned short* __restrict__ onrm, const float* __restrict__ norms,
        float* __restrict__ out, const float* __restrict__ ema_sim,
        const float* __restrict__ part,
        const float* __restrict__ log_tau,
        const float* __restrict__ log_blend,
        const float* __restrict__ logit_blend_seq) {
    int row = blockIdx.x * 4 + (threadIdx.x >> 6);
    int lane = threadIdx.x & 63;
    int b = row >> 11;
    int t = row & (TT - 1);

    int n = 2 * ((t >> 7) + 1);              // 2..32 column-halves present
    float m = (lane < n) ? part[(((size_t)b * 32 + lane) << 11) + t] : -2.0f;
#pragma unroll
    for (int msk = 1; msk < 64; msk <<= 1) m = fmaxf(m, __shfl_xor(m, msk));

    float tau = __expf(log_tau[0]);
    float alpha = 1.f / (1.f + __expf(-log_blend[0]));
    float wseq = 1.f / (1.f + __expf(-logit_blend_seq[0]));
    float es = ema_sim[row];
    float sq = (t > 0) ? m : es;
    float fam = wseq * sq + (1.f - wseq) * es;
    float gate = 1.f - alpha + alpha * __expf(-tau * fam);
    float scale = gate * norms[row];

    const ushort4* ir = reinterpret_cast<const ushort4*>(onrm + (size_t)row * DD);
    float4* orow = reinterpret_cast<float4*>(out + (size_t)row * DD);
#pragma unroll
    for (int j = 0; j < 4; ++j) {
        ushort4 u = ir[j * 64 + lane];
        float4 o;
        o.x = bf2f(u.x) * scale;
        o.y = bf2f(u.y) * scale;
        o.z = bf2f(u.z) * scale;
        o.w = bf2f(u.w) * scale;
        orow[j * 64 + lane] = o;
    }
}

extern "C" void kernel_launch(void* const* d_in, const int* in_sizes, int n_in,
                              void* d_out, int out_size, void* d_ws, size_t ws_size,
                              hipStream_t stream) {
    const float* x = (const float*)d_in[0];
    const float* ema = (const float*)d_in[1];
    // d_in[2] = logit_decay (unused by reference)
    const float* log_tau = (const float*)d_in[3];
    const float* log_blend = (const float*)d_in[4];
    const float* logit_bs = (const float*)d_in[5];
    float* out = (float*)d_out;

    char* ws = (char*)d_ws;
    float* ema_sim = (float*)(ws + (4 << 10));            // 64 KB
    float* norms = (float*)(ws + (68 << 10));             // 64 KB
    float* part = (float*)(ws + (132 << 10));             // 2 MB (8*32*2048 f32)
    unsigned short* onrm = (unsigned short*)(ws + ((size_t)2304 << 10));  // 32 MB

    k_gelu_norm<<<NB * TT / 4, 256, 0, stream>>>(x, ema, onrm, norms, ema_sim);
    k_seqmax<<<NB * NPAIR, 256, 0, stream>>>(onrm, part);
    k_gate<<<NB * TT / 4, 256, 0, stream>>>(onrm, norms, out, ema_sim, part,
                                            log_tau, log_blend, logit_bs);
}